// Round 10
// baseline (305.010 us; speedup 1.0000x reference)
//
#include <hip/hip_runtime.h>
#include <hip/hip_fp16.h>
#include <hip/hip_bf16.h>

// SplineConv MI355X (gfx950). fp32 in/out. R21:
//  - R20 post-mortem: VGPR stayed 52 => compiler re-serialized the chunk
//    issues (source order non-binding); ~2/3 of k_main is un-hidden stall
//    (VALU-bound floor ~16K cy/batch vs 50K observed).
//  - PADDED CSR: recs2[node*64+slot], sentinel {col=0, half(+inf)} for
//    slots deg..63 -> window addr known at t0 (nfo->window serial link
//    GONE), no lane<m masks, k_sort loses the cross-bucket prefix scan.
//    deg>64 overflow -> exact ofl replay (P~0).
//  - FORCED gather burst: per node 8/16 global_load_dwordx2 inline asm
//    ("=&v" u64 outs; ~70 arch + 32 AGPR = 102 <= 128 budget, unlike R15's
//    64-budget failure), one vmcnt(0) pass-through with "+v" ties,
//    sched_barrier(0) pins hat VALU into the latency shadow.
//    Exposures per wave: t0 burst + 1 per node (~3, was ~5).
// Scatter-as-GEMM per node wave + root-folded MFMA epilogue (R9/R10-validated).

#define NN    50000
#define EE    1600000
#define NPB   16             // nodes per block (8 waves x 2 nodes)
#define KD    1664           // 26*64: 25 conv slices + root slice
#define ASTB  1672           // accS row stride (bf16 elems)
#define OFCAP 16384

#define NB    391            // coarse buckets = ceil(NN/128)
#define NSH   4              // shards per bucket
#define CCAP  1280           // per-shard capacity (lambda=1024, +8 sigma)
#define CSTR  16             // ccur stride in u32 (64B pad -> own cacheline)

// prep-kernel grid sections (edges first so they start immediately)
#define REC_B 6250           // EE/256 exactly
#define XB_B  1563           // ceil(NN*64/8/256)
#define WT_B  104            // 64*KD/4/256 exactly

typedef unsigned short ushort_t;
typedef unsigned long long u64_t;
typedef __attribute__((ext_vector_type(8))) short short8;
typedef __attribute__((ext_vector_type(4))) float f32x4;

static __device__ __forceinline__ ushort_t f2bf(float f) {
  union { float f; unsigned u; } v; v.f = f;
  return (ushort_t)((v.u + 0x7fffu + ((v.u >> 16) & 1u)) >> 16);  // RNE
}
static __device__ __forceinline__ unsigned pk2bf(float a, float b) {
  __hip_bfloat162 h = __float22bfloat162_rn(make_float2(a, b));   // v_cvt_pk_bf16_f32
  union { __hip_bfloat162 h; unsigned u; } cv; cv.h = h; return cv.u;
}
union S8 { short8 s; unsigned u[4]; };

// ---------------- K: fused pass A. Sections: [0,REC_B) edges; [.., +XB_B) xb; rest wt.
__global__ __launch_bounds__(256) void k_prep(
    const int* __restrict__ ei, const float* __restrict__ pseudo,
    int* __restrict__ ccur, uint2* __restrict__ coarse,
    const float* __restrict__ x, ushort_t* __restrict__ xb,
    const float* __restrict__ w, const float* __restrict__ root,
    ushort_t* __restrict__ wt, int useXB) {
  const int b = blockIdx.x;
  const int tid = threadIdx.x;
  if (b < REC_B) {
    // ---- coarse scatter: record {col(u16) | row7(u8)<<16, fp16(v0)|fp16(v1)<<16}
    int e = b * 256 + tid;                    // EE == REC_B*256 exactly
    int row = ei[e], col = ei[EE + e];
    float2 pv = ((const float2*)pseudo)[e];
    float v0 = pv.x * 4.0f, v1 = pv.y * 4.0f;
    unsigned h0 = __half_as_ushort(__float2half(v0));
    unsigned h1 = __half_as_ushort(__float2half(v1));
    int c4 = (row >> 7) * NSH + (tid & (NSH - 1));
    int slot = atomicAdd(&ccur[c4 * CSTR], 1);
    if (slot < CCAP)                          // P(overflow) ~ 0 (8 sigma)
      coarse[(size_t)c4 * CCAP + slot] =
          make_uint2((unsigned)col | ((unsigned)(row & 127) << 16), h0 | (h1 << 16));
  } else if (b < REC_B + XB_B) {
    // ---- xb = bf16(x), 8 elems/thread (RNE identical to f2bf)
    if (!useXB) return;
    int t = (b - REC_B) * 256 + tid;
    if (t < NN * 8) {
      const float4* xp = (const float4*)x + (size_t)t * 2;
      float4 aa = xp[0], bb = xp[1];
      S8 o;
      o.u[0] = pk2bf(aa.x, aa.y); o.u[1] = pk2bf(aa.z, aa.w);
      o.u[2] = pk2bf(bb.x, bb.y); o.u[3] = pk2bf(bb.z, bb.w);
      ((short8*)xb)[t] = o.s;
    }
  } else {
    // ---- wt with PERMUTED K-slots: slot c of group kp holds input-feature
    // fi = 4*(c&15) + (c>>4)  (matches B-fragment dwordx2 gather + spill slots)
    int t = (b - REC_B - XB_B) * 256 + tid;
    int idx = t * 4;                          // KD%4==0 -> same o for all 4
    if (idx < 64 * KD) {
      int o = idx / KD, k = idx - o * KD;
#pragma unroll
      for (int q = 0; q < 4; ++q) {
        int kk = k + q;
        int kp = kk >> 6, c = kk & 63;
        int fi = 4 * (c & 15) + (c >> 4);
        wt[idx + q] = (kp < 25) ? f2bf(w[(kp * 64 + fi) * 64 + o])
                                : f2bf(root[fi * 64 + o]);
      }
    }
  }
}

// ---------------- K: pass B. 1 block per coarse bucket -> PADDED CSR (stride
// 64, sentinel-filled) + deg. No cross-bucket scan (start = node*64). Overflow
// (deg>64, P~0) -> exact ofl entries.
__global__ __launch_bounds__(256) void k_sort(
    const int* __restrict__ ccur, const uint2* __restrict__ coarse,
    uint2* __restrict__ recs2, int* __restrict__ degA,
    uint4* __restrict__ ofl, int* __restrict__ ofc) {
  __shared__ int cnt[128], lpos[128];
  const int c = blockIdx.x, tid = threadIdx.x;
  if (tid < 128) cnt[tid] = 0;
  __syncthreads();
  const int pc = c * NSH;
  // count phase (LDS atomics over 128 rows)
  for (int s = 0; s < NSH; ++s) {
    int n = min(ccur[(pc + s) * CSTR], CCAP);
    const uint2* seg = coarse + (size_t)(pc + s) * CCAP;
    for (int i = tid; i < n; i += 256) atomicAdd(&cnt[(seg[i].x >> 16) & 127], 1);
  }
  __syncthreads();
  if (tid < 128) {
    int row = c * 128 + tid;
    lpos[tid] = row * 64;                     // global scatter cursor
    if (row < NN) degA[row] = cnt[tid];
  }
  // sentinel fill for slots cnt..63 (disjoint from scatter targets, no sync)
  for (int i = tid; i < 128 * 64; i += 256) {
    int r7 = i >> 6, sl = i & 63;
    int row = c * 128 + r7;
    if (row < NN && sl >= cnt[r7])
      recs2[(size_t)row * 64 + sl] = make_uint2(0u, 0x7C007C00u);
  }
  __syncthreads();
  // scatter to padded slots; slot>=64 -> ofl (exact replay)
  for (int s = 0; s < NSH; ++s) {
    int n = min(ccur[(pc + s) * CSTR], CCAP);
    const uint2* seg = coarse + (size_t)(pc + s) * CCAP;
    for (int i = tid; i < n; i += 256) {
      uint2 r = seg[i];
      int r7 = (r.x >> 16) & 127;
      int dst = atomicAdd(&lpos[r7], 1);
      int sl = dst - (c * 128 + r7) * 64;
      if (sl < 64) {
        recs2[dst] = make_uint2(r.x & 0xFFFFu, r.y);
      } else {
        int o = atomicAdd(ofc, 1);
        if (o < OFCAP) {
          float v0 = __half2float(__ushort_as_half((ushort_t)(r.y & 0xFFFFu)));
          float v1 = __half2float(__ushort_as_half((ushort_t)(r.y >> 16)));
          ofl[o] = make_uint4((unsigned)(c * 128 + r7), r.x & 0xFFFFu,
                              __float_as_uint(v0), __float_as_uint(v1));
        }
      }
    }
  }
}

// ---------------- forced 8x global_load_dwordx2 burst (compiler CANNOT
// re-serialize: "=&v" outputs stay live until the tied waitcnt)
static __device__ __forceinline__ void issue8(
    const ushort_t* __restrict__ xb, const unsigned (&vo)[8], u64_t (&g)[8]) {
  asm volatile(
      "global_load_dwordx2 %[o0], %[a0], %[sb]\n\t"
      "global_load_dwordx2 %[o1], %[a1], %[sb]\n\t"
      "global_load_dwordx2 %[o2], %[a2], %[sb]\n\t"
      "global_load_dwordx2 %[o3], %[a3], %[sb]\n\t"
      "global_load_dwordx2 %[o4], %[a4], %[sb]\n\t"
      "global_load_dwordx2 %[o5], %[a5], %[sb]\n\t"
      "global_load_dwordx2 %[o6], %[a6], %[sb]\n\t"
      "global_load_dwordx2 %[o7], %[a7], %[sb]\n\t"
      : [o0] "=&v"(g[0]), [o1] "=&v"(g[1]), [o2] "=&v"(g[2]), [o3] "=&v"(g[3]),
        [o4] "=&v"(g[4]), [o5] "=&v"(g[5]), [o6] "=&v"(g[6]), [o7] "=&v"(g[7])
      : [a0] "v"(vo[0]), [a1] "v"(vo[1]), [a2] "v"(vo[2]), [a3] "v"(vo[3]),
        [a4] "v"(vo[4]), [a5] "v"(vo[5]), [a6] "v"(vo[6]), [a7] "v"(vo[7]),
        [sb] "s"(xb));
}
static __device__ __forceinline__ void wait8(u64_t (&g)[8]) {
  asm volatile("s_waitcnt vmcnt(0)"
               : "+v"(g[0]), "+v"(g[1]), "+v"(g[2]), "+v"(g[3]),
                 "+v"(g[4]), "+v"(g[5]), "+v"(g[6]), "+v"(g[7]));
}

// ---------------- shfl window cols -> byte voffsets for one chunk
static __device__ __forceinline__ void vo8(
    unsigned wx, int base, int quad, int m15, unsigned (&vo)[8]) {
#pragma unroll
  for (int j = 0; j < 8; ++j) {
    unsigned c = (unsigned)__shfl((int)wx, base + quad * 8 + j);
    vo[j] = (c << 7) + (unsigned)(m15 << 3);  // col*128 + m15*8
  }
}

// ---------------- hats for one chunk from window pj (sentinel +inf -> 0)
static __device__ __forceinline__ void hats8(
    unsigned wy, int base, int quad, int m15,
    float r0f, float c0f, float r1f, float c1f, S8& aT0, S8& aT1) {
#pragma unroll
  for (int p = 0; p < 4; ++p) {
    float a0[2], a1[2];
#pragma unroll
    for (int q = 0; q < 2; ++q) {
      unsigned pv = (unsigned)__shfl((int)wy, base + quad * 8 + 2 * p + q);
      float v0 = __half2float(__ushort_as_half((ushort_t)(pv & 0xFFFFu)));
      float v1 = __half2float(__ushort_as_half((ushort_t)(pv >> 16)));
      a0[q] = fmaxf(0.f, 1.f - fabsf(v0 - r0f)) * fmaxf(0.f, 1.f - fabsf(v1 - c0f));
      a1[q] = fmaxf(0.f, 1.f - fabsf(v0 - r1f)) * fmaxf(0.f, 1.f - fabsf(v1 - c1f));
    }
    aT0.u[p] = pk2bf(a0[0], a0[1]);
    aT1.u[p] = pk2bf(a1[0], a1[1]);
  }
}

// ---------------- pack staged dwordx2 results + 8 MFMA
static __device__ __forceinline__ void packmfma(
    const u64_t (&g)[8], const S8& aT0, const S8& aT1, f32x4 (&acc)[2][4]) {
  S8 bT[4];
#pragma unroll
  for (int p = 0; p < 4; ++p) {
    unsigned lo0 = (unsigned)g[2 * p],     hi0 = (unsigned)(g[2 * p] >> 32);
    unsigned lo1 = (unsigned)g[2 * p + 1], hi1 = (unsigned)(g[2 * p + 1] >> 32);
    bT[0].u[p] = (lo0 & 0xFFFFu) | (lo1 << 16);
    bT[1].u[p] = (lo0 >> 16)     | (lo1 & 0xFFFF0000u);
    bT[2].u[p] = (hi0 & 0xFFFFu) | (hi1 << 16);
    bT[3].u[p] = (hi0 >> 16)     | (hi1 & 0xFFFF0000u);
  }
  __builtin_amdgcn_s_setprio(1);
#pragma unroll
  for (int t = 0; t < 4; ++t) {
    acc[0][t] = __builtin_amdgcn_mfma_f32_16x16x32_bf16(aT0.s, bT[t].s, acc[0][t], 0, 0, 0);
    acc[1][t] = __builtin_amdgcn_mfma_f32_16x16x32_bf16(aT1.s, bT[t].s, acc[1][t], 0, 0, 0);
  }
  __builtin_amdgcn_s_setprio(0);
}

// ---------------- one node, bf16 path: forced-burst pipeline
static __device__ __forceinline__ void node_bf16(
    unsigned wx, unsigned wy, int m, int quad, int m15,
    float r0f, float c0f, float r1f, float c1f,
    const ushort_t* __restrict__ xb, f32x4 (&acc)[2][4]) {
  if (m > 32) {
    unsigned vo0[8], vo1[8];
    u64_t g0[8], g1[8];
    vo8(wx, 0, quad, m15, vo0);
    issue8(xb, vo0, g0);
    vo8(wx, 32, quad, m15, vo1);
    issue8(xb, vo1, g1);                  // 16 dwordx2 in flight
    S8 aT0_0, aT1_0, aT0_1, aT1_1;
    hats8(wy, 0,  quad, m15, r0f, c0f, r1f, c1f, aT0_0, aT1_0);
    hats8(wy, 32, quad, m15, r0f, c0f, r1f, c1f, aT0_1, aT1_1);
    __builtin_amdgcn_sched_barrier(0);    // pin hats before the wait
    wait8(g0); wait8(g1);
    packmfma(g0, aT0_0, aT1_0, acc);
    packmfma(g1, aT0_1, aT1_1, acc);
  } else {
    unsigned vo0[8];
    u64_t g0[8];
    vo8(wx, 0, quad, m15, vo0);
    issue8(xb, vo0, g0);
    S8 aT0, aT1;
    hats8(wy, 0, quad, m15, r0f, c0f, r1f, c1f, aT0, aT1);
    __builtin_amdgcn_sched_barrier(0);
    wait8(g0);
    packmfma(g0, aT0, aT1, acc);
  }
}

// ---------------- ofl replay (deg>64 only; expected count 0)
static __device__ __forceinline__ void replay_ofl(
    const uint4* __restrict__ ofl, int ofcv, int node, int quad, int m15,
    float r0f, float c0f, float r1f, float c1f,
    const float* __restrict__ x, f32x4 (&acc)[2][4]) {
  for (int i = 0; i < ofcv; ++i) {
    uint4 r = ofl[i];
    if ((int)r.x != node) continue;       // wave-uniform
    float v0 = __uint_as_float(r.z), v1 = __uint_as_float(r.w);
    float h00 = fmaxf(0.f, 1.f - fabsf(v0 - r0f));
    float h01 = fmaxf(0.f, 1.f - fabsf(v1 - c0f));
    float h10 = fmaxf(0.f, 1.f - fabsf(v0 - r1f));
    float h11 = fmaxf(0.f, 1.f - fabsf(v1 - c1f));
    float mk = (quad == 0) ? 1.0f : 0.0f; // edge occupies k=0 only
    S8 aT0, aT1, bT[4];
#pragma unroll
    for (int p = 0; p < 4; ++p) { aT0.u[p] = 0; aT1.u[p] = 0; }
    aT0.u[0] = pk2bf(h00 * h01 * mk, 0.0f);
    aT1.u[0] = pk2bf(h10 * h11 * mk, 0.0f);
    float4 xv = *(const float4*)(x + (size_t)r.y * 64 + (m15 << 2));  // permuted feats
    float fv[4] = {xv.x, xv.y, xv.z, xv.w};
#pragma unroll
    for (int t = 0; t < 4; ++t)
#pragma unroll
      for (int p = 0; p < 4; ++p) bT[t].u[p] = pk2bf(fv[t], fv[t]);   // A zeros mask
#pragma unroll
    for (int t = 0; t < 4; ++t) {
      acc[0][t] = __builtin_amdgcn_mfma_f32_16x16x32_bf16(aT0.s, bT[t].s, acc[0][t], 0, 0, 0);
      acc[1][t] = __builtin_amdgcn_mfma_f32_16x16x32_bf16(aT1.s, bT[t].s, acc[1][t], 0, 0, 0);
    }
  }
}

// ---------------- masked direct-load chunk (fp32 fallback path)
static __device__ __forceinline__ void do_chunk_f32(
    const uint2 (&rq)[8], int kb, int m, int quad, int m15,
    float r0f, float c0f, float r1f, float c1f,
    const float* __restrict__ x, f32x4 (&acc)[2][4]) {
  unsigned cj[8], pj[8];
#pragma unroll
  for (int j = 0; j < 8; ++j) {
    cj[j] = min(rq[j].x, (unsigned)(NN - 1));
    pj[j] = rq[j].y;
  }
  float gf[4][8];
#pragma unroll
  for (int j = 0; j < 8; ++j) {
    float4 v = *(const float4*)(x + ((size_t)cj[j] << 6) + (m15 << 2));
    gf[0][j] = v.x; gf[1][j] = v.y; gf[2][j] = v.z; gf[3][j] = v.w;
  }
  S8 aT0, aT1, bT[4];
#pragma unroll
  for (int p = 0; p < 4; ++p) {
    float a0[2], a1[2];
#pragma unroll
    for (int q = 0; q < 2; ++q) {
      int j = 2 * p + q;
      unsigned pv = pj[j];
      float v0 = __half2float(__ushort_as_half((ushort_t)(pv & 0xFFFFu)));
      float v1 = __half2float(__ushort_as_half((ushort_t)(pv >> 16)));
      bool ok = (kb + quad * 8 + j) < m;
      float p0 = fmaxf(0.f, 1.f - fabsf(v0 - r0f)) * fmaxf(0.f, 1.f - fabsf(v1 - c0f));
      float p1 = fmaxf(0.f, 1.f - fabsf(v0 - r1f)) * fmaxf(0.f, 1.f - fabsf(v1 - c1f));
      a0[q] = ok ? p0 : 0.0f;
      a1[q] = ok ? p1 : 0.0f;
    }
    aT0.u[p] = pk2bf(a0[0], a0[1]);
    aT1.u[p] = pk2bf(a1[0], a1[1]);
  }
#pragma unroll
  for (int p = 0; p < 4; ++p)
#pragma unroll
    for (int t = 0; t < 4; ++t)
      bT[t].u[p] = pk2bf(gf[t][2 * p], gf[t][2 * p + 1]);
#pragma unroll
  for (int t = 0; t < 4; ++t) {
    acc[0][t] = __builtin_amdgcn_mfma_f32_16x16x32_bf16(aT0.s, bT[t].s, acc[0][t], 0, 0, 0);
    acc[1][t] = __builtin_amdgcn_mfma_f32_16x16x32_bf16(aT1.s, bT[t].s, acc[1][t], 0, 0, 0);
  }
}

// ---------------- spill acc -> accS (kp = mt*16 + quad*4 + r, slot = nt*16+m15)
static __device__ __forceinline__ void spill_acc(
    ushort_t* accS, int row, int quad, int m15, const f32x4 (&acc)[2][4]) {
#pragma unroll
  for (int mt = 0; mt < 2; ++mt)
#pragma unroll
    for (int r = 0; r < 4; ++r) {
      int kp = mt * 16 + quad * 4 + r;
      if (kp < 25) {
#pragma unroll
        for (int nt = 0; nt < 4; ++nt)
          accS[row * ASTB + kp * 64 + nt * 16 + m15] = f2bf(acc[mt][nt][r]);
      }
    }
}

// ---------------- K: main fused. 1 block = 16 nodes, 8 waves x 2 nodes.
// launch_bounds(512,4) = 128-reg budget; 16 waves/CU (proven no-spill region).
template <bool XBF>
__global__ __launch_bounds__(512, 4) void k_main(
    const uint2* __restrict__ recs2, const int* __restrict__ degA,
    const uint4* __restrict__ ofl, const int* __restrict__ ofc,
    const float* __restrict__ x, const ushort_t* __restrict__ xb,
    const ushort_t* __restrict__ wt, const float* __restrict__ bias,
    float* __restrict__ out) {
  __shared__ ushort_t accS[NPB * ASTB];   // 53.5 KB, bf16, MFMA-A layout
  __shared__ float    outp[2 * NPB * 64]; // 8 KB, per-kh partials (2 halves)
  __shared__ float    sinv[NPB];
  const int tid = threadIdx.x;
  const int lane = tid & 63;
  const int w = tid >> 6;                 // wave id in [0,8)
  const int nb = blockIdx.x * NPB;

  const int m15 = lane & 15, quad = lane >> 4;
  const float r0f = (float)(m15 / 5),        c0f = (float)(m15 % 5);
  const float r1f = (float)((16 + m15) / 5), c1f = (float)((16 + m15) % 5);
  const int fl = 4 * m15 + quad;          // permuted feature for slot=lane

  const int rowA = w << 1, rowB = rowA + 1;
  const int nodeA = nb + rowA, nodeB = nb + rowB;

  // ---- t0 burst: ALL independent (padded CSR: window addr = node*64, no nfo
  // dependency). degs, windows, roots, ofc issue together.
  const int mA = degA[nodeA], mB = degA[nodeB];
  uint2 wA = recs2[(size_t)nodeA * 64 + lane];   // sentinel-padded, no mask
  uint2 wB = recs2[(size_t)nodeB * 64 + lane];
  const float rxA = x[(size_t)nodeA * 64 + fl];
  const float rxB = x[(size_t)nodeB * 64 + fl];
  const int ofcv = min(ofc[0], OFCAP);

  const float dcfA = (float)max(mA, 1), dcfB = (float)max(mB, 1);
  if (lane == 0) { sinv[rowA] = 1.0f / dcfA; sinv[rowB] = 1.0f / dcfB; }
  accS[rowA * ASTB + 1600 + lane] = f2bf(rxA * dcfA);
  accS[rowB * ASTB + 1600 + lane] = f2bf(rxB * dcfB);

  f32x4 acc[2][4];
#pragma unroll
  for (int a = 0; a < 2; ++a)
#pragma unroll
    for (int b = 0; b < 4; ++b) acc[a][b] = (f32x4){0.f, 0.f, 0.f, 0.f};

  if (XBF) {
    node_bf16(wA.x, wA.y, mA, quad, m15, r0f, c0f, r1f, c1f, xb, acc);
    if (ofcv) replay_ofl(ofl, ofcv, nodeA, quad, m15, r0f, c0f, r1f, c1f, x, acc);
    spill_acc(accS, rowA, quad, m15, acc);
#pragma unroll
    for (int a = 0; a < 2; ++a)
#pragma unroll
      for (int b = 0; b < 4; ++b) acc[a][b] = (f32x4){0.f, 0.f, 0.f, 0.f};
    node_bf16(wB.x, wB.y, mB, quad, m15, r0f, c0f, r1f, c1f, xb, acc);
    if (ofcv) replay_ofl(ofl, ofcv, nodeB, quad, m15, r0f, c0f, r1f, c1f, x, acc);
    spill_acc(accS, rowB, quad, m15, acc);
  } else {
    // ---- fp32 fallback: masked direct-load chunks from padded CSR + replay
    for (int e0 = 0; e0 < min(mA, 64); e0 += 32) {
      uint2 rq[8];
#pragma unroll
      for (int j = 0; j < 8; ++j) rq[j] = recs2[(size_t)nodeA * 64 + e0 + quad * 8 + j];
      do_chunk_f32(rq, e0, mA, quad, m15, r0f, c0f, r1f, c1f, x, acc);
    }
    if (ofcv) replay_ofl(ofl, ofcv, nodeA, quad, m15, r0f, c0f, r1f, c1f, x, acc);
    spill_acc(accS, rowA, quad, m15, acc);
#pragma unroll
    for (int a = 0; a < 2; ++a)
#pragma unroll
      for (int b = 0; b < 4; ++b) acc[a][b] = (f32x4){0.f, 0.f, 0.f, 0.f};
    for (int e0 = 0; e0 < min(mB, 64); e0 += 32) {
      uint2 rq[8];
#pragma unroll
      for (int j = 0; j < 8; ++j) rq[j] = recs2[(size_t)nodeB * 64 + e0 + quad * 8 + j];
      do_chunk_f32(rq, e0, mB, quad, m15, r0f, c0f, r1f, c1f, x, acc);
    }
    if (ofcv) replay_ofl(ofl, ofcv, nodeB, quad, m15, r0f, c0f, r1f, c1f, x, acc);
    spill_acc(accS, rowB, quad, m15, acc);
  }
  __syncthreads();

  {  // MFMA epilogue: D[16 nodes][64] = accS[16][1664] @ wt^T
    // 8 waves: ntile = w&3 (output quarter), kh = w>>2 (K half, 26 kk each).
    // wt fragments prefetched depth-6 into statically-indexed regs.
    const int ntile = w & 3, kh = w >> 2;
    const int m2 = lane & 15, quad2 = lane >> 4;
    const int nn2 = ntile * 16 + m2;
    f32x4 d = {0.0f, 0.0f, 0.0f, 0.0f};
    const ushort_t* ab = &accS[m2 * ASTB + kh * 832 + quad2 * 8];
    const ushort_t* wb = &wt[(size_t)nn2 * KD + kh * 832 + quad2 * 8];
    short8 bfs[6];
#pragma unroll
    for (int kk = 0; kk < 6; ++kk) bfs[kk] = *(const short8*)(wb + kk * 32);
#pragma unroll
    for (int kk = 0; kk < 26; ++kk) {
      short8 af = *(const short8*)(ab + kk * 32);
      d = __builtin_amdgcn_mfma_f32_16x16x32_bf16(af, bfs[kk % 6], d, 0, 0, 0);
      if (kk + 6 < 26) bfs[kk % 6] = *(const short8*)(wb + (kk + 6) * 32);
    }
#pragma unroll
    for (int r = 0; r < 4; ++r)
      outp[kh * (NPB * 64) + (quad2 * 4 + r) * 64 + ntile * 16 + m2] = d[r];
  }
  __syncthreads();

  {  // final: out = (conv + x*dc@root) * (1/dc) + bias; 512 threads x 2 elems
#pragma unroll
    for (int h = 0; h < 2; ++h) {
      int i = h * 512 + tid;
      int nl = i >> 6, o = i & 63;
      float conv = outp[i] + outp[NPB * 64 + i];
      out[(size_t)(nb + nl) * 64 + o] = conv * sinv[nl] + bias[o];
    }
  }
}

// ---------------- sentinel: unambiguous "workspace too small" signature
__global__ void k_sentinel(float* __restrict__ out) {
  int i = blockIdx.x * 256 + threadIdx.x;
  if (i < NN * 64) out[i] = 1000.0f;
}

extern "C" void kernel_launch(void* const* d_in, const int* in_sizes, int n_in,
                              void* d_out, int out_size, void* d_ws, size_t ws_size,
                              hipStream_t stream) {
  const float* x      = (const float*)d_in[0];
  const int*   ei     = (const int*)d_in[1];
  const float* pseudo = (const float*)d_in[2];
  const float* w      = (const float*)d_in[3];
  const float* root   = (const float*)d_in[4];
  const float* bias   = (const float*)d_in[5];
  float* out = (float*)d_out;
  (void)in_sizes; (void)n_in; (void)out_size;

  char* ws = (char*)d_ws;
  size_t off = 0;
  auto alloc = [&](size_t bytes) { size_t r = off; off += (bytes + 511) & ~(size_t)511; return r; };
  ushort_t* wt     = (ushort_t*)(ws + alloc((size_t)64 * KD * 2));          // 213 KB
  int*      ccur   = (int*)(ws + alloc((size_t)(NB * NSH * CSTR + 16) * 4));// 100 KB (+ofc)
  int*      ofcp   = ccur + NB * NSH * CSTR;                                // zeroed with ccur
  int*      degA   = (int*)(ws + alloc((size_t)NN * 4));                    // 200 KB
  uint4*    ofl    = (uint4*)(ws + alloc((size_t)OFCAP * 16));              // 256 KB
  uint2*    recs2  = (uint2*)(ws + alloc((size_t)NN * 64 * 8));             // 25.6 MB (padded CSR)
  uint2*    coarse = (uint2*)(ws + alloc((size_t)NB * NSH * CCAP * 8));     // 16.0 MB
  size_t baseNeed  = off;
  ushort_t* xb     = (ushort_t*)(ws + alloc((size_t)NN * 64 * 2));          // 6.4 MB (optional)
  size_t fullNeed  = off;

  if (ws_size < baseNeed) {
    k_sentinel<<<(NN * 64 + 255) / 256, 256, 0, stream>>>(out);
    return;
  }
  const int useXB = (ws_size >= fullNeed) ? 1 : 0;

  hipMemsetAsync(ccur, 0, (size_t)(NB * NSH * CSTR + 16) * 4, stream);
  k_prep<<<REC_B + XB_B + WT_B, 256, 0, stream>>>(ei, pseudo, ccur, coarse,
                                                  x, xb, w, root, wt, useXB);
  k_sort<<<NB, 256, 0, stream>>>(ccur, coarse, recs2, degA, ofl, ofcp);
  if (useXB)
    k_main<true><<<NN / NPB, 512, 0, stream>>>(recs2, degA, ofl, ofcp, x, xb, wt, bias, out);
  else
    k_main<false><<<NN / NPB, 512, 0, stream>>>(recs2, degA, ofl, ofcp, x, xb, wt, bias, out);
}